// Round 4
// baseline (229.588 us; speedup 1.0000x reference)
//
#include <hip/hip_runtime.h>
#include <math.h>

#define D 256

__device__ __forceinline__ float wave_reduce_sum(float v) {
#pragma unroll
    for (int off = 32; off > 0; off >>= 1) v += __shfl_xor(v, off);
    return v;
}

__device__ __forceinline__ unsigned short f2bf_rne(float f) {
    unsigned int u = __float_as_uint(f);
    u += 0x7fffu + ((u >> 16) & 1u);   // round-to-nearest-even
    return (unsigned short)(u >> 16);
}
__device__ __forceinline__ float bf2f(unsigned short h) {
    return __uint_as_float((unsigned int)h << 16);
}

// Gather one 256-elem embedding row spread across 64 lanes (4 elems/lane).
template <bool BF16>
__device__ __forceinline__ float4 load_row(const float* __restrict__ E_w,
                                           const unsigned short* __restrict__ Eb,
                                           int idx, int lane) {
    if (BF16) {
        const ushort4 h = ((const ushort4*)(Eb + (size_t)idx * D))[lane];
        return make_float4(bf2f(h.x), bf2f(h.y), bf2f(h.z), bf2f(h.w));
    } else {
        return ((const float4*)(E_w + (size_t)idx * D))[lane];
    }
}

// ---------------------------------------------------------------------------
// Prologue: E_w fp32 -> bf16 into d_ws. Streaming 102 MB read + 51 MB write.
// Must rerun every launch (d_ws is re-poisoned by the harness).
// ---------------------------------------------------------------------------
__global__ __launch_bounds__(256) void convert_bf16_kernel(
    const float* __restrict__ E_w, unsigned short* __restrict__ Eb, int n4) {
    const int stride = gridDim.x * 256;
    for (int i = blockIdx.x * 256 + threadIdx.x; i < n4; i += stride) {
        const float4 v = ((const float4*)E_w)[i];
        ushort4 o;
        o.x = f2bf_rne(v.x); o.y = f2bf_rne(v.y);
        o.z = f2bf_rne(v.z); o.w = f2bf_rne(v.w);
        ((ushort4*)Eb)[i] = o;
    }
}

// ---------------------------------------------------------------------------
// Fused kernel, 256 threads = 4 waves per block.
//   blocks [0, B)       : "main" path for batch row b
//   blocks [B, B + B*M) : "negs" path for pair bm
// R3 counters: fabric-bound at ~2.85 TB/s on ~300 MB of L2-missed random row
// gathers. BF16=true halves gather bytes (the only remaining lever).
// ---------------------------------------------------------------------------
template <bool BF16>
__global__ __launch_bounds__(256) void abae_fused_kernel(
    const int* __restrict__ pos, const int* __restrict__ negs,
    const float* __restrict__ E_w, const unsigned short* __restrict__ Eb,
    const float* __restrict__ T_w, const float* __restrict__ M_w,
    const float* __restrict__ M_b, const float* __restrict__ lin_w,
    const float* __restrict__ lin_b, float* __restrict__ r_s,
    float* __restrict__ z_s, float* __restrict__ z_n, int B, int L, int n_asp) {
    const int t    = threadIdx.x;
    const int lane = t & 63;
    const int wv   = t >> 6;            // 0..3

    __shared__ float4 sred[4][64];
    __shared__ float  sy[D];            // y_s, later z_s
    __shared__ float  smy[D];           // My
    __shared__ float  slog[16];
    __shared__ float  sp[16];
    __shared__ float  sscal[4];

    if (blockIdx.x >= B) {
        // ================= negs path: z_n[bm] = l2norm(mean_l E[negs]) ======
        const int bm = blockIdx.x - B;
        const int* __restrict__ idxp = negs + (size_t)bm * L;
        const int C  = (L + 3) / 4;     // 25 tokens per wave
        const int s0 = wv * C;
        const int e0 = min(L, s0 + C);

        float4 acc = make_float4(0.f, 0.f, 0.f, 0.f);
        int l = s0;
        for (; l + 5 <= e0; l += 5) {   // 5 gathers in flight per lane
            const int i0 = idxp[l], i1 = idxp[l + 1], i2 = idxp[l + 2],
                      i3 = idxp[l + 3], i4 = idxp[l + 4];
            const float4 v0 = load_row<BF16>(E_w, Eb, i0, lane);
            const float4 v1 = load_row<BF16>(E_w, Eb, i1, lane);
            const float4 v2 = load_row<BF16>(E_w, Eb, i2, lane);
            const float4 v3 = load_row<BF16>(E_w, Eb, i3, lane);
            const float4 v4 = load_row<BF16>(E_w, Eb, i4, lane);
            acc.x += v0.x + v1.x + v2.x + v3.x + v4.x;
            acc.y += v0.y + v1.y + v2.y + v3.y + v4.y;
            acc.z += v0.z + v1.z + v2.z + v3.z + v4.z;
            acc.w += v0.w + v1.w + v2.w + v3.w + v4.w;
        }
        for (; l < e0; ++l) {
            const float4 v = load_row<BF16>(E_w, Eb, idxp[l], lane);
            acc.x += v.x; acc.y += v.y; acc.z += v.z; acc.w += v.w;
        }
        sred[wv][lane] = acc;
        __syncthreads();
        if (wv == 0) {
            float4 z  = sred[0][lane];
            const float4 a1 = sred[1][lane], a2 = sred[2][lane], a3 = sred[3][lane];
            const float invL = 1.f / (float)L;
            z.x = (z.x + a1.x + a2.x + a3.x) * invL;
            z.y = (z.y + a1.y + a2.y + a3.y) * invL;
            z.z = (z.z + a1.z + a2.z + a3.z) * invL;
            z.w = (z.w + a1.w + a2.w + a3.w) * invL;
            float ss = z.x * z.x + z.y * z.y + z.z * z.z + z.w * z.w;
            ss = wave_reduce_sum(ss);
            const float inv = 1.f / fmaxf(sqrtf(ss), 1e-12f);
            z.x *= inv; z.y *= inv; z.z *= inv; z.w *= inv;
            ((float4*)(z_n + (size_t)bm * D))[lane] = z;
        }
        return;
    }

    // ==================== main path: batch row b ============================
    const int b = blockIdx.x;
    const int* __restrict__ posb = pos + (size_t)b * L;
    const int C  = (L + 3) / 4;
    const int s0 = wv * C;
    const int e0 = min(L, s0 + C);

    // ---- phase 1: y_s = mean_l E[pos[b,l]] ----
    float4 acc = make_float4(0.f, 0.f, 0.f, 0.f);
    int l = s0;
    for (; l + 4 <= e0; l += 4) {
        const int i0 = posb[l], i1 = posb[l + 1], i2 = posb[l + 2], i3 = posb[l + 3];
        const float4 v0 = load_row<BF16>(E_w, Eb, i0, lane);
        const float4 v1 = load_row<BF16>(E_w, Eb, i1, lane);
        const float4 v2 = load_row<BF16>(E_w, Eb, i2, lane);
        const float4 v3 = load_row<BF16>(E_w, Eb, i3, lane);
        acc.x += v0.x + v1.x + v2.x + v3.x;
        acc.y += v0.y + v1.y + v2.y + v3.y;
        acc.z += v0.z + v1.z + v2.z + v3.z;
        acc.w += v0.w + v1.w + v2.w + v3.w;
    }
    for (; l < e0; ++l) {
        const float4 v = load_row<BF16>(E_w, Eb, posb[l], lane);
        acc.x += v.x; acc.y += v.y; acc.z += v.z; acc.w += v.w;
    }
    sred[wv][lane] = acc;
    __syncthreads();
    if (wv == 0) {
        float4 y  = sred[0][lane];
        const float4 a1 = sred[1][lane], a2 = sred[2][lane], a3 = sred[3][lane];
        const float invL = 1.f / (float)L;
        y.x = (y.x + a1.x + a2.x + a3.x) * invL;
        y.y = (y.y + a1.y + a2.y + a3.y) * invL;
        y.z = (y.z + a1.z + a2.z + a3.z) * invL;
        y.w = (y.w + a1.w + a2.w + a3.w) * invL;
        ((float4*)sy)[lane] = y;
    }
    __syncthreads();

    // ---- phase 2: My[r] = M_b[r] + M_w[r,:] . y_s — wave-per-row coalesced,
    // 4 rows in flight, shuffle-reduce (M_w stays fp32; L2-resident).
    {
        const float4 y4 = ((const float4*)sy)[lane];
        for (int r0 = wv * 64; r0 < wv * 64 + 64; r0 += 4) {
            const float4 m0 = ((const float4*)(M_w + (size_t)(r0 + 0) * D))[lane];
            const float4 m1 = ((const float4*)(M_w + (size_t)(r0 + 1) * D))[lane];
            const float4 m2 = ((const float4*)(M_w + (size_t)(r0 + 2) * D))[lane];
            const float4 m3 = ((const float4*)(M_w + (size_t)(r0 + 3) * D))[lane];
            float p0 = m0.x * y4.x + m0.y * y4.y + m0.z * y4.z + m0.w * y4.w;
            float p1 = m1.x * y4.x + m1.y * y4.y + m1.z * y4.z + m1.w * y4.w;
            float p2 = m2.x * y4.x + m2.y * y4.y + m2.z * y4.z + m2.w * y4.w;
            float p3 = m3.x * y4.x + m3.y * y4.y + m3.z * y4.z + m3.w * y4.w;
#pragma unroll
            for (int off = 32; off > 0; off >>= 1) {
                p0 += __shfl_xor(p0, off);
                p1 += __shfl_xor(p1, off);
                p2 += __shfl_xor(p2, off);
                p3 += __shfl_xor(p3, off);
            }
            if (lane == 0) {
                smy[r0 + 0] = p0 + M_b[r0 + 0];
                smy[r0 + 1] = p1 + M_b[r0 + 1];
                smy[r0 + 2] = p2 + M_b[r0 + 2];
                smy[r0 + 3] = p3 + M_b[r0 + 3];
            }
        }
    }
    __syncthreads();

    // ---- phase 3: z = sum_l e_l * exp(tanh(e_l . My)) ----
    const float4 my4 = ((const float4*)smy)[lane];
    float4 zacc = make_float4(0.f, 0.f, 0.f, 0.f);
    l = s0;
    for (; l + 1 < e0; l += 2) {
        const float4 ea = load_row<BF16>(E_w, Eb, posb[l], lane);
        const float4 eb = load_row<BF16>(E_w, Eb, posb[l + 1], lane);
        float pa = ea.x * my4.x + ea.y * my4.y + ea.z * my4.z + ea.w * my4.w;
        float pb = eb.x * my4.x + eb.y * my4.y + eb.z * my4.z + eb.w * my4.w;
#pragma unroll
        for (int off = 32; off > 0; off >>= 1) {
            pa += __shfl_xor(pa, off);
            pb += __shfl_xor(pb, off);
        }
        const float wa = expf(tanhf(pa));
        const float wb = expf(tanhf(pb));
        zacc.x += ea.x * wa + eb.x * wb;
        zacc.y += ea.y * wa + eb.y * wb;
        zacc.z += ea.z * wa + eb.z * wb;
        zacc.w += ea.w * wa + eb.w * wb;
    }
    for (; l < e0; ++l) {
        const float4 ea = load_row<BF16>(E_w, Eb, posb[l], lane);
        float pa = ea.x * my4.x + ea.y * my4.y + ea.z * my4.z + ea.w * my4.w;
        pa = wave_reduce_sum(pa);
        const float wa = expf(tanhf(pa));
        zacc.x += ea.x * wa; zacc.y += ea.y * wa;
        zacc.z += ea.z * wa; zacc.w += ea.w * wa;
    }
    sred[wv][lane] = zacc;
    __syncthreads();
    if (wv == 0) {
        float4 z  = sred[0][lane];
        const float4 a1 = sred[1][lane], a2 = sred[2][lane], a3 = sred[3][lane];
        z.x += a1.x + a2.x + a3.x;
        z.y += a1.y + a2.y + a3.y;
        z.z += a1.z + a2.z + a3.z;
        z.w += a1.w + a2.w + a3.w;
        float ss = z.x * z.x + z.y * z.y + z.z * z.z + z.w * z.w;
        ss = wave_reduce_sum(ss);
        const float inv = 1.f / fmaxf(sqrtf(ss), 1e-12f);
        z.x *= inv; z.y *= inv; z.z *= inv; z.w *= inv;
        ((float4*)(z_s + (size_t)b * D))[lane] = z;   // output 1: z_s
        ((float4*)sy)[lane] = z;                      // sy := z_s
    }
    __syncthreads();

    // ---- phase 4: p = softmax(z_s @ lin_w.T + lin_b) ----
    const float4 z4 = ((const float4*)sy)[lane];
    for (int a = wv; a < n_asp; a += 4) {
        const float4 w4 = ((const float4*)(lin_w + (size_t)a * D))[lane];
        float p = z4.x * w4.x + z4.y * w4.y + z4.z * w4.z + z4.w * w4.w;
        p = wave_reduce_sum(p);
        if (lane == 0) slog[a] = p + lin_b[a];
    }
    __syncthreads();
    if (t == 0) {
        float mx = -1e30f;
        for (int a = 0; a < n_asp; ++a) mx = fmaxf(mx, slog[a]);
        float s = 0.f;
        for (int a = 0; a < n_asp; ++a) {
            const float e = expf(slog[a] - mx);
            sp[a] = e; s += e;
        }
        const float invs = 1.f / s;
        for (int a = 0; a < n_asp; ++a) sp[a] *= invs;
    }
    __syncthreads();

    // ---- phase 5: r_s = l2norm(p @ T_w) ----
    float r = 0.f;
    for (int a = 0; a < n_asp; ++a) r += sp[a] * T_w[(size_t)a * D + t];
    const float sq = wave_reduce_sum(r * r);
    if (lane == 0) sscal[wv] = sq;
    __syncthreads();
    const float tot = sscal[0] + sscal[1] + sscal[2] + sscal[3];
    const float inv = 1.f / fmaxf(sqrtf(tot), 1e-12f);
    r_s[(size_t)b * D + t] = r * inv;                 // output 0: r_s
}

extern "C" void kernel_launch(void* const* d_in, const int* in_sizes, int n_in,
                              void* d_out, int out_size, void* d_ws, size_t ws_size,
                              hipStream_t stream) {
    const int*   pos   = (const int*)d_in[0];
    const int*   negs  = (const int*)d_in[1];
    const float* E_w   = (const float*)d_in[2];
    const float* T_w   = (const float*)d_in[3];
    const float* M_w   = (const float*)d_in[4];
    const float* M_b   = (const float*)d_in[5];
    const float* lin_w = (const float*)d_in[6];
    const float* lin_b = (const float*)d_in[7];
    float* out = (float*)d_out;

    const int d     = in_sizes[5];                 // 256 (M_b)
    const int n_asp = in_sizes[7];                 // 14  (lin_b)
    const int M     = in_sizes[1] / in_sizes[0];   // 10
    const int B     = out_size / (d * (2 + M));    // 512
    const int L     = in_sizes[0] / B;             // 100
    (void)d; (void)n_in;

    float* r_s = out;                              // [B, d]
    float* z_s = out + (size_t)B * d;              // [B, d]
    float* z_n = out + (size_t)2 * B * d;          // [B, M, d]

    const size_t ew_elems = (size_t)in_sizes[2];   // n_vocab * d
    const bool use_bf16 = ws_size >= ew_elems * sizeof(unsigned short);

    if (use_bf16) {
        unsigned short* Eb = (unsigned short*)d_ws;
        convert_bf16_kernel<<<2048, 256, 0, stream>>>(E_w, Eb, (int)(ew_elems / 4));
        abae_fused_kernel<true><<<B + B * M, 256, 0, stream>>>(
            pos, negs, E_w, Eb, T_w, M_w, M_b, lin_w, lin_b,
            r_s, z_s, z_n, B, L, n_asp);
    } else {
        abae_fused_kernel<false><<<B + B * M, 256, 0, stream>>>(
            pos, negs, E_w, (const unsigned short*)nullptr, T_w, M_w, M_b,
            lin_w, lin_b, r_s, z_s, z_n, B, L, n_asp);
    }
}

// Round 5
// 218.971 us; speedup vs baseline: 1.0485x; 1.0485x over previous
//
#include <hip/hip_runtime.h>
#include <math.h>

#define D 256

__device__ __forceinline__ float wave_reduce_sum(float v) {
#pragma unroll
    for (int off = 32; off > 0; off >>= 1) v += __shfl_xor(v, off);
    return v;
}
__device__ __forceinline__ float wave_reduce_max(float v) {
#pragma unroll
    for (int off = 32; off > 0; off >>= 1) v = fmaxf(v, __shfl_xor(v, off));
    return v;
}

// ---------------------------------------------------------------------------
// K1: blocks [0,B)           -> main path (fp32, error-critical)
//     blocks [B, B+NCONV)    -> quantize E_w rows to int8 + per-row scale
// The two groups use disjoint resources (main = latency/barrier-bound with
// ~52 MB of gathers; convert = HBM streaming), so K1 ~ max(25us, 25us).
// Stream ordering makes the int8 table ready before K2.
// ---------------------------------------------------------------------------
__global__ __launch_bounds__(256) void abae_main_convert_kernel(
    const int* __restrict__ pos, const float* __restrict__ E_w,
    const float* __restrict__ T_w, const float* __restrict__ M_w,
    const float* __restrict__ M_b, const float* __restrict__ lin_w,
    const float* __restrict__ lin_b, float* __restrict__ r_s,
    float* __restrict__ z_s, signed char* __restrict__ Eq,
    float* __restrict__ scales, int B, int L, int n_asp, int n_vocab,
    int nconv) {
    const int t    = threadIdx.x;
    const int lane = t & 63;
    const int wv   = t >> 6;            // 0..3

    if (blockIdx.x >= B) {
        // ================== convert path: wave-per-row int8 quantize ========
        const int cb = blockIdx.x - B;
        for (int r = cb * 4 + wv; r < n_vocab; r += nconv * 4) {
            const float4 v = ((const float4*)(E_w + (size_t)r * D))[lane];
            float mx = fmaxf(fmaxf(fabsf(v.x), fabsf(v.y)),
                             fmaxf(fabsf(v.z), fabsf(v.w)));
            mx = wave_reduce_max(mx);
            const float scale = mx * (1.f / 127.f);
            const float inv   = (mx > 0.f) ? 127.f / mx : 0.f;
            int qx = __float2int_rn(v.x * inv);
            int qy = __float2int_rn(v.y * inv);
            int qz = __float2int_rn(v.z * inv);
            int qw = __float2int_rn(v.w * inv);
            qx = max(-127, min(127, qx)); qy = max(-127, min(127, qy));
            qz = max(-127, min(127, qz)); qw = max(-127, min(127, qw));
            const unsigned int packed =
                ((unsigned int)(unsigned char)(signed char)qx) |
                ((unsigned int)(unsigned char)(signed char)qy << 8) |
                ((unsigned int)(unsigned char)(signed char)qz << 16) |
                ((unsigned int)(unsigned char)(signed char)qw << 24);
            ((unsigned int*)(Eq + (size_t)r * D))[lane] = packed;
            if (lane == 0) scales[r] = scale;
        }
        return;
    }

    // ==================== main path: batch row b (fp32) =====================
    __shared__ float4 sred[4][64];
    __shared__ float  sy[D];            // y_s, later z_s
    __shared__ float  smy[D];           // My
    __shared__ float  slog[16];
    __shared__ float  sp[16];
    __shared__ float  sscal[4];

    const int b = blockIdx.x;
    const int* __restrict__ posb = pos + (size_t)b * L;
    const int C  = (L + 3) / 4;
    const int s0 = wv * C;
    const int e0 = min(L, s0 + C);

    // ---- phase 1: y_s = mean_l E_w[pos[b,l]] ----
    float4 acc = make_float4(0.f, 0.f, 0.f, 0.f);
    int l = s0;
    for (; l + 4 <= e0; l += 4) {
        const int i0 = posb[l], i1 = posb[l + 1], i2 = posb[l + 2], i3 = posb[l + 3];
        const float4 v0 = ((const float4*)(E_w + (size_t)i0 * D))[lane];
        const float4 v1 = ((const float4*)(E_w + (size_t)i1 * D))[lane];
        const float4 v2 = ((const float4*)(E_w + (size_t)i2 * D))[lane];
        const float4 v3 = ((const float4*)(E_w + (size_t)i3 * D))[lane];
        acc.x += v0.x + v1.x + v2.x + v3.x;
        acc.y += v0.y + v1.y + v2.y + v3.y;
        acc.z += v0.z + v1.z + v2.z + v3.z;
        acc.w += v0.w + v1.w + v2.w + v3.w;
    }
    for (; l < e0; ++l) {
        const float4 v = ((const float4*)(E_w + (size_t)posb[l] * D))[lane];
        acc.x += v.x; acc.y += v.y; acc.z += v.z; acc.w += v.w;
    }
    sred[wv][lane] = acc;
    __syncthreads();
    if (wv == 0) {
        float4 y  = sred[0][lane];
        const float4 a1 = sred[1][lane], a2 = sred[2][lane], a3 = sred[3][lane];
        const float invL = 1.f / (float)L;
        y.x = (y.x + a1.x + a2.x + a3.x) * invL;
        y.y = (y.y + a1.y + a2.y + a3.y) * invL;
        y.z = (y.z + a1.z + a2.z + a3.z) * invL;
        y.w = (y.w + a1.w + a2.w + a3.w) * invL;
        ((float4*)sy)[lane] = y;
    }
    __syncthreads();

    // ---- phase 2: My[r] = M_b[r] + M_w[r,:] . y_s — wave-per-row coalesced
    {
        const float4 y4 = ((const float4*)sy)[lane];
        for (int r0 = wv * 64; r0 < wv * 64 + 64; r0 += 4) {
            const float4 m0 = ((const float4*)(M_w + (size_t)(r0 + 0) * D))[lane];
            const float4 m1 = ((const float4*)(M_w + (size_t)(r0 + 1) * D))[lane];
            const float4 m2 = ((const float4*)(M_w + (size_t)(r0 + 2) * D))[lane];
            const float4 m3 = ((const float4*)(M_w + (size_t)(r0 + 3) * D))[lane];
            float p0 = m0.x * y4.x + m0.y * y4.y + m0.z * y4.z + m0.w * y4.w;
            float p1 = m1.x * y4.x + m1.y * y4.y + m1.z * y4.z + m1.w * y4.w;
            float p2 = m2.x * y4.x + m2.y * y4.y + m2.z * y4.z + m2.w * y4.w;
            float p3 = m3.x * y4.x + m3.y * y4.y + m3.z * y4.z + m3.w * y4.w;
#pragma unroll
            for (int off = 32; off > 0; off >>= 1) {
                p0 += __shfl_xor(p0, off);
                p1 += __shfl_xor(p1, off);
                p2 += __shfl_xor(p2, off);
                p3 += __shfl_xor(p3, off);
            }
            if (lane == 0) {
                smy[r0 + 0] = p0 + M_b[r0 + 0];
                smy[r0 + 1] = p1 + M_b[r0 + 1];
                smy[r0 + 2] = p2 + M_b[r0 + 2];
                smy[r0 + 3] = p3 + M_b[r0 + 3];
            }
        }
    }
    __syncthreads();

    // ---- phase 3: z = sum_l e_l * exp(tanh(e_l . My)) — rows L2-warm ----
    const float4 my4 = ((const float4*)smy)[lane];
    float4 zacc = make_float4(0.f, 0.f, 0.f, 0.f);
    l = s0;
    for (; l + 1 < e0; l += 2) {
        const float4 ea = ((const float4*)(E_w + (size_t)posb[l] * D))[lane];
        const float4 eb = ((const float4*)(E_w + (size_t)posb[l + 1] * D))[lane];
        float pa = ea.x * my4.x + ea.y * my4.y + ea.z * my4.z + ea.w * my4.w;
        float pb = eb.x * my4.x + eb.y * my4.y + eb.z * my4.z + eb.w * my4.w;
#pragma unroll
        for (int off = 32; off > 0; off >>= 1) {
            pa += __shfl_xor(pa, off);
            pb += __shfl_xor(pb, off);
        }
        const float wa = expf(tanhf(pa));
        const float wb = expf(tanhf(pb));
        zacc.x += ea.x * wa + eb.x * wb;
        zacc.y += ea.y * wa + eb.y * wb;
        zacc.z += ea.z * wa + eb.z * wb;
        zacc.w += ea.w * wa + eb.w * wb;
    }
    for (; l < e0; ++l) {
        const float4 ea = ((const float4*)(E_w + (size_t)posb[l] * D))[lane];
        float pa = ea.x * my4.x + ea.y * my4.y + ea.z * my4.z + ea.w * my4.w;
        pa = wave_reduce_sum(pa);
        const float wa = expf(tanhf(pa));
        zacc.x += ea.x * wa; zacc.y += ea.y * wa;
        zacc.z += ea.z * wa; zacc.w += ea.w * wa;
    }
    sred[wv][lane] = zacc;
    __syncthreads();
    if (wv == 0) {
        float4 z  = sred[0][lane];
        const float4 a1 = sred[1][lane], a2 = sred[2][lane], a3 = sred[3][lane];
        z.x += a1.x + a2.x + a3.x;
        z.y += a1.y + a2.y + a3.y;
        z.z += a1.z + a2.z + a3.z;
        z.w += a1.w + a2.w + a3.w;
        float ss = z.x * z.x + z.y * z.y + z.z * z.z + z.w * z.w;
        ss = wave_reduce_sum(ss);
        const float inv = 1.f / fmaxf(sqrtf(ss), 1e-12f);
        z.x *= inv; z.y *= inv; z.z *= inv; z.w *= inv;
        ((float4*)(z_s + (size_t)b * D))[lane] = z;   // output 1: z_s
        ((float4*)sy)[lane] = z;                      // sy := z_s
    }
    __syncthreads();

    // ---- phase 4: p = softmax(z_s @ lin_w.T + lin_b) ----
    const float4 z4 = ((const float4*)sy)[lane];
    for (int a = wv; a < n_asp; a += 4) {
        const float4 w4 = ((const float4*)(lin_w + (size_t)a * D))[lane];
        float p = z4.x * w4.x + z4.y * w4.y + z4.z * w4.z + z4.w * w4.w;
        p = wave_reduce_sum(p);
        if (lane == 0) slog[a] = p + lin_b[a];
    }
    __syncthreads();
    if (t == 0) {
        float mx = -1e30f;
        for (int a = 0; a < n_asp; ++a) mx = fmaxf(mx, slog[a]);
        float s = 0.f;
        for (int a = 0; a < n_asp; ++a) {
            const float e = expf(slog[a] - mx);
            sp[a] = e; s += e;
        }
        const float invs = 1.f / s;
        for (int a = 0; a < n_asp; ++a) sp[a] *= invs;
    }
    __syncthreads();

    // ---- phase 5: r_s = l2norm(p @ T_w) ----
    float r = 0.f;
    for (int a = 0; a < n_asp; ++a) r += sp[a] * T_w[(size_t)a * D + t];
    const float sq = wave_reduce_sum(r * r);
    if (lane == 0) sscal[wv] = sq;
    __syncthreads();
    const float tot = sscal[0] + sscal[1] + sscal[2] + sscal[3];
    const float inv = 1.f / fmaxf(sqrtf(tot), 1e-12f);
    r_s[(size_t)b * D + t] = r * inv;                 // output 0: r_s
}

// ---------------------------------------------------------------------------
// K2: z_n[bm] = l2norm(mean_l dequant(Eq[negs])). One block per (b,m).
// int8 rows = 256 B (char4/lane, one dword load) — quarter of R3's fp32 bytes
// on the ~2.45 TB/s fabric wall. I8=false is the no-workspace fallback.
// ---------------------------------------------------------------------------
template <bool I8>
__global__ __launch_bounds__(256) void abae_negs_kernel(
    const int* __restrict__ negs, const float* __restrict__ E_w,
    const signed char* __restrict__ Eq, const float* __restrict__ scales,
    float* __restrict__ z_n, int L) {
    const int bm   = blockIdx.x;
    const int t    = threadIdx.x;
    const int lane = t & 63;
    const int wv   = t >> 6;
    const int* __restrict__ idxp = negs + (size_t)bm * L;

    const int C  = (L + 3) / 4;       // 25 tokens per wave
    const int s0 = wv * C;
    const int e0 = min(L, s0 + C);

    float4 acc = make_float4(0.f, 0.f, 0.f, 0.f);
    int l = s0;
    if (I8) {
        for (; l + 5 <= e0; l += 5) {   // 5 row-loads + 5 scale-loads in flight
            const int i0 = idxp[l], i1 = idxp[l + 1], i2 = idxp[l + 2],
                      i3 = idxp[l + 3], i4 = idxp[l + 4];
            const char4 c0 = ((const char4*)(Eq + (size_t)i0 * D))[lane];
            const char4 c1 = ((const char4*)(Eq + (size_t)i1 * D))[lane];
            const char4 c2 = ((const char4*)(Eq + (size_t)i2 * D))[lane];
            const char4 c3 = ((const char4*)(Eq + (size_t)i3 * D))[lane];
            const char4 c4 = ((const char4*)(Eq + (size_t)i4 * D))[lane];
            const float f0 = scales[i0], f1 = scales[i1], f2 = scales[i2],
                        f3 = scales[i3], f4 = scales[i4];
            acc.x += f0 * (float)c0.x + f1 * (float)c1.x + f2 * (float)c2.x +
                     f3 * (float)c3.x + f4 * (float)c4.x;
            acc.y += f0 * (float)c0.y + f1 * (float)c1.y + f2 * (float)c2.y +
                     f3 * (float)c3.y + f4 * (float)c4.y;
            acc.z += f0 * (float)c0.z + f1 * (float)c1.z + f2 * (float)c2.z +
                     f3 * (float)c3.z + f4 * (float)c4.z;
            acc.w += f0 * (float)c0.w + f1 * (float)c1.w + f2 * (float)c2.w +
                     f3 * (float)c3.w + f4 * (float)c4.w;
        }
        for (; l < e0; ++l) {
            const int i = idxp[l];
            const char4 c = ((const char4*)(Eq + (size_t)i * D))[lane];
            const float f = scales[i];
            acc.x += f * (float)c.x; acc.y += f * (float)c.y;
            acc.z += f * (float)c.z; acc.w += f * (float)c.w;
        }
    } else {
        for (; l < e0; ++l) {
            const float4 v = ((const float4*)(E_w + (size_t)idxp[l] * D))[lane];
            acc.x += v.x; acc.y += v.y; acc.z += v.z; acc.w += v.w;
        }
    }

    __shared__ float4 sred[4][64];
    sred[wv][lane] = acc;
    __syncthreads();
    if (wv == 0) {
        float4 z  = sred[0][lane];
        const float4 a1 = sred[1][lane], a2 = sred[2][lane], a3 = sred[3][lane];
        const float invL = 1.f / (float)L;
        z.x = (z.x + a1.x + a2.x + a3.x) * invL;
        z.y = (z.y + a1.y + a2.y + a3.y) * invL;
        z.z = (z.z + a1.z + a2.z + a3.z) * invL;
        z.w = (z.w + a1.w + a2.w + a3.w) * invL;
        float ss = z.x * z.x + z.y * z.y + z.z * z.z + z.w * z.w;
        ss = wave_reduce_sum(ss);
        const float inv = 1.f / fmaxf(sqrtf(ss), 1e-12f);
        z.x *= inv; z.y *= inv; z.z *= inv; z.w *= inv;
        ((float4*)(z_n + (size_t)bm * D))[lane] = z;
    }
}

// fp32-everything fallback main kernel is just K1 with nconv=0.

extern "C" void kernel_launch(void* const* d_in, const int* in_sizes, int n_in,
                              void* d_out, int out_size, void* d_ws, size_t ws_size,
                              hipStream_t stream) {
    const int*   pos   = (const int*)d_in[0];
    const int*   negs  = (const int*)d_in[1];
    const float* E_w   = (const float*)d_in[2];
    const float* T_w   = (const float*)d_in[3];
    const float* M_w   = (const float*)d_in[4];
    const float* M_b   = (const float*)d_in[5];
    const float* lin_w = (const float*)d_in[6];
    const float* lin_b = (const float*)d_in[7];
    float* out = (float*)d_out;

    const int d       = in_sizes[5];                 // 256 (M_b)
    const int n_asp   = in_sizes[7];                 // 14  (lin_b)
    const int M       = in_sizes[1] / in_sizes[0];   // 10
    const int B       = out_size / (d * (2 + M));    // 512
    const int L       = in_sizes[0] / B;             // 100
    const int n_vocab = in_sizes[2] / d;             // 100000
    (void)n_in;

    float* r_s = out;                              // [B, d]
    float* z_s = out + (size_t)B * d;              // [B, d]
    float* z_n = out + (size_t)2 * B * d;          // [B, M, d]

    const size_t need = (size_t)n_vocab * D + (size_t)n_vocab * sizeof(float);
    const bool use_i8 = ws_size >= need;

    signed char* Eq  = (signed char*)d_ws;
    float* scales    = (float*)(Eq + (size_t)n_vocab * D);

    const int nconv = use_i8 ? 3584 : 0;
    abae_main_convert_kernel<<<B + nconv, 256, 0, stream>>>(
        pos, E_w, T_w, M_w, M_b, lin_w, lin_b, r_s, z_s, Eq, scales,
        B, L, n_asp, n_vocab, nconv);

    if (use_i8) {
        abae_negs_kernel<true><<<B * M, 256, 0, stream>>>(
            negs, E_w, Eq, scales, z_n, L);
    } else {
        abae_negs_kernel<false><<<B * M, 256, 0, stream>>>(
            negs, E_w, (const signed char*)nullptr, (const float*)nullptr, z_n, L);
    }
}

// Round 6
// 217.028 us; speedup vs baseline: 1.0579x; 1.0090x over previous
//
#include <hip/hip_runtime.h>
#include <math.h>

#define D 256

__device__ __forceinline__ float wave_reduce_sum(float v) {
#pragma unroll
    for (int off = 32; off > 0; off >>= 1) v += __shfl_xor(v, off);
    return v;
}
__device__ __forceinline__ float wave_reduce_max(float v) {
#pragma unroll
    for (int off = 32; off > 0; off >>= 1) v = fmaxf(v, __shfl_xor(v, off));
    return v;
}

// Row loaders: one 256-elem embedding row spread over 64 lanes (4 elems/lane).
__device__ __forceinline__ float4 load_row_f32(const float* __restrict__ E_w,
                                               int idx, int lane) {
    return ((const float4*)(E_w + (size_t)idx * D))[lane];
}
__device__ __forceinline__ float4 load_row_i8(const signed char* __restrict__ Eq,
                                              const float* __restrict__ scales,
                                              int idx, int lane) {
    const char4 c = ((const char4*)(Eq + (size_t)idx * D))[lane];  // 256B row
    const float f = scales[idx];                                    // broadcast
    return make_float4(f * (float)c.x, f * (float)c.y,
                       f * (float)c.z, f * (float)c.w);
}
template <bool I8>
__device__ __forceinline__ float4 load_row(const float* __restrict__ E_w,
                                           const signed char* __restrict__ Eq,
                                           const float* __restrict__ scales,
                                           int idx, int lane) {
    return I8 ? load_row_i8(Eq, scales, idx, lane) : load_row_f32(E_w, idx, lane);
}

// ---------------------------------------------------------------------------
// K0: E_w fp32 -> int8 + per-row scale. Wave-per-row, 4 rows batched per
// iteration so 4 x 1KB loads are in flight before the reduce chains (R5's
// version had 1 load in flight -> suspected latency serialization).
// n_vocab is divisible by 4 (100000); guarded anyway.
// ---------------------------------------------------------------------------
__global__ __launch_bounds__(256) void convert_i8_kernel(
    const float* __restrict__ E_w, signed char* __restrict__ Eq,
    float* __restrict__ scales, int n_vocab) {
    const int lane = threadIdx.x & 63;
    const int gw   = (blockIdx.x * 256 + threadIdx.x) >> 6;  // global wave id
    const int nw   = (gridDim.x * 256) >> 6;

    for (int r0 = gw * 4; r0 < n_vocab; r0 += nw * 4) {
        const int n = min(4, n_vocab - r0);
        float4 v[4];
#pragma unroll
        for (int k = 0; k < 4; ++k)
            if (k < n) v[k] = load_row_f32(E_w, r0 + k, lane);
#pragma unroll
        for (int k = 0; k < 4; ++k) {
            if (k >= n) break;
            float mx = fmaxf(fmaxf(fabsf(v[k].x), fabsf(v[k].y)),
                             fmaxf(fabsf(v[k].z), fabsf(v[k].w)));
            mx = wave_reduce_max(mx);
            const float inv = (mx > 0.f) ? 127.f / mx : 0.f;
            int qx = __float2int_rn(v[k].x * inv);
            int qy = __float2int_rn(v[k].y * inv);
            int qz = __float2int_rn(v[k].z * inv);
            int qw = __float2int_rn(v[k].w * inv);
            const unsigned int packed =
                ((unsigned int)(unsigned char)(signed char)qx) |
                ((unsigned int)(unsigned char)(signed char)qy << 8) |
                ((unsigned int)(unsigned char)(signed char)qz << 16) |
                ((unsigned int)(unsigned char)(signed char)qw << 24);
            ((unsigned int*)(Eq + (size_t)(r0 + k) * D))[lane] = packed;
            if (lane == 0) scales[r0 + k] = mx * (1.f / 127.f);
        }
    }
}

// ---------------------------------------------------------------------------
// K1: blocks [0,B)       -> main path for batch row b
//     blocks [B, B+B*M)  -> negs path for pair bm
// Both paths gather from the int8 table (256B rows): main drops 104->26 MB
// logical and shares L3-hot rows with negs. I8=false = no-workspace fallback.
// ---------------------------------------------------------------------------
template <bool I8>
__global__ __launch_bounds__(256) void abae_fused_kernel(
    const int* __restrict__ pos, const int* __restrict__ negs,
    const float* __restrict__ E_w, const signed char* __restrict__ Eq,
    const float* __restrict__ scales, const float* __restrict__ T_w,
    const float* __restrict__ M_w, const float* __restrict__ M_b,
    const float* __restrict__ lin_w, const float* __restrict__ lin_b,
    float* __restrict__ r_s, float* __restrict__ z_s, float* __restrict__ z_n,
    int B, int L, int n_asp) {
    const int t    = threadIdx.x;
    const int lane = t & 63;
    const int wv   = t >> 6;            // 0..3

    __shared__ float4 sred[4][64];
    __shared__ float  sy[D];            // y_s, later z_s
    __shared__ float  smy[D];           // My
    __shared__ float  slog[16];
    __shared__ float  sp[16];
    __shared__ float  sscal[4];

    const int C = (L + 3) / 4;          // tokens per wave (25)

    if (blockIdx.x >= B) {
        // ================= negs path: z_n[bm] = l2norm(mean_l E[negs]) ======
        const int bm = blockIdx.x - B;
        const int* __restrict__ idxp = negs + (size_t)bm * L;
        const int s0 = wv * C;
        const int e0 = min(L, s0 + C);

        float4 acc = make_float4(0.f, 0.f, 0.f, 0.f);
        int l = s0;
        for (; l + 5 <= e0; l += 5) {   // 5 gathers in flight per lane
            const int i0 = idxp[l], i1 = idxp[l + 1], i2 = idxp[l + 2],
                      i3 = idxp[l + 3], i4 = idxp[l + 4];
            const float4 v0 = load_row<I8>(E_w, Eq, scales, i0, lane);
            const float4 v1 = load_row<I8>(E_w, Eq, scales, i1, lane);
            const float4 v2 = load_row<I8>(E_w, Eq, scales, i2, lane);
            const float4 v3 = load_row<I8>(E_w, Eq, scales, i3, lane);
            const float4 v4 = load_row<I8>(E_w, Eq, scales, i4, lane);
            acc.x += v0.x + v1.x + v2.x + v3.x + v4.x;
            acc.y += v0.y + v1.y + v2.y + v3.y + v4.y;
            acc.z += v0.z + v1.z + v2.z + v3.z + v4.z;
            acc.w += v0.w + v1.w + v2.w + v3.w + v4.w;
        }
        for (; l < e0; ++l) {
            const float4 v = load_row<I8>(E_w, Eq, scales, idxp[l], lane);
            acc.x += v.x; acc.y += v.y; acc.z += v.z; acc.w += v.w;
        }
        sred[wv][lane] = acc;
        __syncthreads();
        if (wv == 0) {
            float4 z  = sred[0][lane];
            const float4 a1 = sred[1][lane], a2 = sred[2][lane], a3 = sred[3][lane];
            const float invL = 1.f / (float)L;
            z.x = (z.x + a1.x + a2.x + a3.x) * invL;
            z.y = (z.y + a1.y + a2.y + a3.y) * invL;
            z.z = (z.z + a1.z + a2.z + a3.z) * invL;
            z.w = (z.w + a1.w + a2.w + a3.w) * invL;
            float ss = z.x * z.x + z.y * z.y + z.z * z.z + z.w * z.w;
            ss = wave_reduce_sum(ss);
            const float inv = 1.f / fmaxf(sqrtf(ss), 1e-12f);
            z.x *= inv; z.y *= inv; z.z *= inv; z.w *= inv;
            ((float4*)(z_n + (size_t)bm * D))[lane] = z;
        }
        return;
    }

    // ==================== main path: batch row b ============================
    const int b = blockIdx.x;
    const int* __restrict__ posb = pos + (size_t)b * L;
    const int s0 = wv * C;
    const int e0 = min(L, s0 + C);

    // ---- phase 1: y_s = mean_l E[pos[b,l]], 4 gathers in flight ----
    float4 acc = make_float4(0.f, 0.f, 0.f, 0.f);
    int l = s0;
    for (; l + 4 <= e0; l += 4) {
        const int i0 = posb[l], i1 = posb[l + 1], i2 = posb[l + 2], i3 = posb[l + 3];
        const float4 v0 = load_row<I8>(E_w, Eq, scales, i0, lane);
        const float4 v1 = load_row<I8>(E_w, Eq, scales, i1, lane);
        const float4 v2 = load_row<I8>(E_w, Eq, scales, i2, lane);
        const float4 v3 = load_row<I8>(E_w, Eq, scales, i3, lane);
        acc.x += v0.x + v1.x + v2.x + v3.x;
        acc.y += v0.y + v1.y + v2.y + v3.y;
        acc.z += v0.z + v1.z + v2.z + v3.z;
        acc.w += v0.w + v1.w + v2.w + v3.w;
    }
    for (; l < e0; ++l) {
        const float4 v = load_row<I8>(E_w, Eq, scales, posb[l], lane);
        acc.x += v.x; acc.y += v.y; acc.z += v.z; acc.w += v.w;
    }
    sred[wv][lane] = acc;
    __syncthreads();
    if (wv == 0) {
        float4 y  = sred[0][lane];
        const float4 a1 = sred[1][lane], a2 = sred[2][lane], a3 = sred[3][lane];
        const float invL = 1.f / (float)L;
        y.x = (y.x + a1.x + a2.x + a3.x) * invL;
        y.y = (y.y + a1.y + a2.y + a3.y) * invL;
        y.z = (y.z + a1.z + a2.z + a3.z) * invL;
        y.w = (y.w + a1.w + a2.w + a3.w) * invL;
        ((float4*)sy)[lane] = y;
    }
    __syncthreads();

    // ---- phase 2: My[r] = M_b[r] + M_w[r,:] . y_s — wave-per-row coalesced,
    // 4 rows in flight (M_w stays fp32; L2/L3-resident).
    {
        const float4 y4 = ((const float4*)sy)[lane];
        for (int r0 = wv * 64; r0 < wv * 64 + 64; r0 += 4) {
            const float4 m0 = ((const float4*)(M_w + (size_t)(r0 + 0) * D))[lane];
            const float4 m1 = ((const float4*)(M_w + (size_t)(r0 + 1) * D))[lane];
            const float4 m2 = ((const float4*)(M_w + (size_t)(r0 + 2) * D))[lane];
            const float4 m3 = ((const float4*)(M_w + (size_t)(r0 + 3) * D))[lane];
            float p0 = m0.x * y4.x + m0.y * y4.y + m0.z * y4.z + m0.w * y4.w;
            float p1 = m1.x * y4.x + m1.y * y4.y + m1.z * y4.z + m1.w * y4.w;
            float p2 = m2.x * y4.x + m2.y * y4.y + m2.z * y4.z + m2.w * y4.w;
            float p3 = m3.x * y4.x + m3.y * y4.y + m3.z * y4.z + m3.w * y4.w;
#pragma unroll
            for (int off = 32; off > 0; off >>= 1) {
                p0 += __shfl_xor(p0, off);
                p1 += __shfl_xor(p1, off);
                p2 += __shfl_xor(p2, off);
                p3 += __shfl_xor(p3, off);
            }
            if (lane == 0) {
                smy[r0 + 0] = p0 + M_b[r0 + 0];
                smy[r0 + 1] = p1 + M_b[r0 + 1];
                smy[r0 + 2] = p2 + M_b[r0 + 2];
                smy[r0 + 3] = p3 + M_b[r0 + 3];
            }
        }
    }
    __syncthreads();

    // ---- phase 3: z = sum_l e_l * exp(tanh(e_l . My)); rows L3-warm ----
    const float4 my4 = ((const float4*)smy)[lane];
    float4 zacc = make_float4(0.f, 0.f, 0.f, 0.f);
    l = s0;
    for (; l + 1 < e0; l += 2) {
        const float4 ea = load_row<I8>(E_w, Eq, scales, posb[l], lane);
        const float4 eb = load_row<I8>(E_w, Eq, scales, posb[l + 1], lane);
        float pa = ea.x * my4.x + ea.y * my4.y + ea.z * my4.z + ea.w * my4.w;
        float pb = eb.x * my4.x + eb.y * my4.y + eb.z * my4.z + eb.w * my4.w;
#pragma unroll
        for (int off = 32; off > 0; off >>= 1) {
            pa += __shfl_xor(pa, off);
            pb += __shfl_xor(pb, off);
        }
        const float wa = expf(tanhf(pa));
        const float wb = expf(tanhf(pb));
        zacc.x += ea.x * wa + eb.x * wb;
        zacc.y += ea.y * wa + eb.y * wb;
        zacc.z += ea.z * wa + eb.z * wb;
        zacc.w += ea.w * wa + eb.w * wb;
    }
    for (; l < e0; ++l) {
        const float4 ea = load_row<I8>(E_w, Eq, scales, posb[l], lane);
        float pa = ea.x * my4.x + ea.y * my4.y + ea.z * my4.z + ea.w * my4.w;
        pa = wave_reduce_sum(pa);
        const float wa = expf(tanhf(pa));
        zacc.x += ea.x * wa; zacc.y += ea.y * wa;
        zacc.z += ea.z * wa; zacc.w += ea.w * wa;
    }
    sred[wv][lane] = zacc;
    __syncthreads();
    if (wv == 0) {
        float4 z  = sred[0][lane];
        const float4 a1 = sred[1][lane], a2 = sred[2][lane], a3 = sred[3][lane];
        z.x += a1.x + a2.x + a3.x;
        z.y += a1.y + a2.y + a3.y;
        z.z += a1.z + a2.z + a3.z;
        z.w += a1.w + a2.w + a3.w;
        float ss = z.x * z.x + z.y * z.y + z.z * z.z + z.w * z.w;
        ss = wave_reduce_sum(ss);
        const float inv = 1.f / fmaxf(sqrtf(ss), 1e-12f);
        z.x *= inv; z.y *= inv; z.z *= inv; z.w *= inv;
        ((float4*)(z_s + (size_t)b * D))[lane] = z;   // output 1: z_s
        ((float4*)sy)[lane] = z;                      // sy := z_s
    }
    __syncthreads();

    // ---- phase 4: p = softmax(z_s @ lin_w.T + lin_b) ----
    const float4 z4 = ((const float4*)sy)[lane];
    for (int a = wv; a < n_asp; a += 4) {
        const float4 w4 = ((const float4*)(lin_w + (size_t)a * D))[lane];
        float p = z4.x * w4.x + z4.y * w4.y + z4.z * w4.z + z4.w * w4.w;
        p = wave_reduce_sum(p);
        if (lane == 0) slog[a] = p + lin_b[a];
    }
    __syncthreads();
    if (t == 0) {
        float mx = -1e30f;
        for (int a = 0; a < n_asp; ++a) mx = fmaxf(mx, slog[a]);
        float s = 0.f;
        for (int a = 0; a < n_asp; ++a) {
            const float e = expf(slog[a] - mx);
            sp[a] = e; s += e;
        }
        const float invs = 1.f / s;
        for (int a = 0; a < n_asp; ++a) sp[a] *= invs;
    }
    __syncthreads();

    // ---- phase 5: r_s = l2norm(p @ T_w) ----
    float r = 0.f;
    for (int a = 0; a < n_asp; ++a) r += sp[a] * T_w[(size_t)a * D + t];
    const float sq = wave_reduce_sum(r * r);
    if (lane == 0) sscal[wv] = sq;
    __syncthreads();
    const float tot = sscal[0] + sscal[1] + sscal[2] + sscal[3];
    const float inv = 1.f / fmaxf(sqrtf(tot), 1e-12f);
    r_s[(size_t)b * D + t] = r * inv;                 // output 0: r_s
}

extern "C" void kernel_launch(void* const* d_in, const int* in_sizes, int n_in,
                              void* d_out, int out_size, void* d_ws, size_t ws_size,
                              hipStream_t stream) {
    const int*   pos   = (const int*)d_in[0];
    const int*   negs  = (const int*)d_in[1];
    const float* E_w   = (const float*)d_in[2];
    const float* T_w   = (const float*)d_in[3];
    const float* M_w   = (const float*)d_in[4];
    const float* M_b   = (const float*)d_in[5];
    const float* lin_w = (const float*)d_in[6];
    const float* lin_b = (const float*)d_in[7];
    float* out = (float*)d_out;

    const int d       = in_sizes[5];                 // 256 (M_b)
    const int n_asp   = in_sizes[7];                 // 14  (lin_b)
    const int M       = in_sizes[1] / in_sizes[0];   // 10
    const int B       = out_size / (d * (2 + M));    // 512
    const int L       = in_sizes[0] / B;             // 100
    const int n_vocab = in_sizes[2] / d;             // 100000
    (void)n_in;

    float* r_s = out;                              // [B, d]
    float* z_s = out + (size_t)B * d;              // [B, d]
    float* z_n = out + (size_t)2 * B * d;          // [B, M, d]

    const size_t need = (size_t)n_vocab * D + (size_t)n_vocab * sizeof(float);
    const bool use_i8 = ws_size >= need;

    signed char* Eq = (signed char*)d_ws;
    float* scales   = (float*)(Eq + (size_t)n_vocab * D);

    if (use_i8) {
        convert_i8_kernel<<<2048, 256, 0, stream>>>(E_w, Eq, scales, n_vocab);
        abae_fused_kernel<true><<<B + B * M, 256, 0, stream>>>(
            pos, negs, E_w, Eq, scales, T_w, M_w, M_b, lin_w, lin_b,
            r_s, z_s, z_n, B, L, n_asp);
    } else {
        abae_fused_kernel<false><<<B + B * M, 256, 0, stream>>>(
            pos, negs, E_w, (const signed char*)nullptr, (const float*)nullptr,
            T_w, M_w, M_b, lin_w, lin_b, r_s, z_s, z_n, B, L, n_asp);
    }
}